// Round 18
// baseline (85.772 us; speedup 1.0000x reference)
//
#include <hip/hip_runtime.h>
#include <hip/hip_fp16.h>

#define BINS 10

typedef float f32x4 __attribute__((ext_vector_type(4)));  // native vec for nt-load

__device__ __forceinline__ unsigned pk_add_f16x2(unsigned a, unsigned b) {
    __half2 ha = __builtin_bit_cast(__half2, a);
    __half2 hb = __builtin_bit_cast(__half2, b);
    return __builtin_bit_cast(unsigned, __hadd2(ha, hb));   // v_pk_add_f16
}

// ===== ELEM MATH: byte-for-byte from R2/R8/R13/R15 (PASSED absmax 0.0). The
// z-form (R3-R7) fails on HW — banned. LDS atomics (R8/R14) and volatile RMW
// chains (R9) banned. Scatter: packed-f16 pair accumulators (R15, passed).
__device__ __forceinline__ void ghm_elem(float x, float tt,
                                         unsigned long long& pk,
                                         unsigned (&acc)[5]) {
    float t = __expf(-fabsf(x));                 // e^{-|x|}
    float u = 1.f + t;
    float r = __builtin_amdgcn_rcpf(u);          // ~1ulp approx, ample slack
    float sig = (x >= 0.f) ? r : t * r;          // sigmoid(x), all ranges
    float d = sig - tt;
    int idx = (int)(fabsf(d) * 10.f);            // trunc (validated R8/R10)
    idx = idx < 9 ? idx : 9;
    pk += 1ull << (6 * idx);                     // packed counts, 6b/bin
    float bce = fmaxf(x, 0.f) - x * tt + __logf(u);  // log1p(e^{-|x|}) = log(u)
    unsigned hv = (unsigned)__builtin_bit_cast(unsigned short, __float2half(bce));
    hv <<= ((idx & 1) << 4);                     // place in low/high half
    const int pair = idx >> 1;
#pragma unroll
    for (int p = 0; p < 5; ++p)                  // cmp + cndmask + pk_add
        acc[p] = pk_add_f16x2(acc[p], (pair == p) ? hv : 0u);
}

// Fused kernel, FIXED-POINT GLOBAL-ATOMIC epilogue.
// R16: __threadfence = per-block buffer_wbl2 -> 321us. R17: winner reduced
// 20K partials via agent atomic loads, each waited -> ~45us serial tail.
// R18: cross-block state is just 20 u64 accumulators. Each block atomicAdds
// v*2^26 (u64 fixed point: integer adds are exact+commutative -> bit-
// deterministic for any block order) and counts. 20480 int atomics over 20
// addresses pipeline at the L3 slices (~us, overlapped). Winner reads 20
// values (one latency), computes the final divide.
__global__ __launch_bounds__(256) void ghm_fused(
    const float* __restrict__ pred, const float* __restrict__ tgt,
    long long n, int nb,
    unsigned long long* __restrict__ gsum,   // [BINS] fixed-point 2^26
    unsigned long long* __restrict__ gcnt,   // [BINS]
    unsigned int* __restrict__ done, float* __restrict__ out)
{
    __shared__ float rsum[4][BINS];
    __shared__ int   rcnt[4][BINS];

    const int tid  = threadIdx.x;
    const int lane = tid & 63;
    const int wave = tid >> 6;

    float s[BINS];
#pragma unroll
    for (int b = 0; b < BINS; ++b) s[b] = 0.f;
    unsigned acc[5];
#pragma unroll
    for (int p = 0; p < 5; ++p) acc[p] = 0u;
    unsigned long long pk = 0;
    int c[BINS];
#pragma unroll
    for (int b = 0; b < BINS; ++b) c[b] = 0;

    const long long n4 = n >> 2;
    const f32x4* p4 = (const f32x4*)pred;
    const f32x4* t4 = (const f32x4*)tgt;

    // Chunked contiguous partition + NT loads (R13, proven 51->40us).
    const long long qpb = (n4 + nb - 1) / nb;
    const long long q0  = (long long)blockIdx.x * qpb;
    const long long q1  = (q0 + qpb < n4) ? (q0 + qpb) : n4;

    int chunk = 0;
    for (long long i = q0 + tid; i < q1; i += 512) {   // unroll x2
        f32x4 pa = __builtin_nontemporal_load(&p4[i]);
        f32x4 ta = __builtin_nontemporal_load(&t4[i]);
        const long long j = i + 256;
        f32x4 pb, tb;
        const bool has2 = (j < q1);
        if (has2) {
            pb = __builtin_nontemporal_load(&p4[j]);
            tb = __builtin_nontemporal_load(&t4[j]);
        }
        ghm_elem(pa.x, ta.x, pk, acc);
        ghm_elem(pa.y, ta.y, pk, acc);
        ghm_elem(pa.z, ta.z, pk, acc);
        ghm_elem(pa.w, ta.w, pk, acc);
        if (has2) {
            ghm_elem(pb.x, tb.x, pk, acc);
            ghm_elem(pb.y, tb.y, pk, acc);
            ghm_elem(pb.z, tb.z, pk, acc);
            ghm_elem(pb.w, tb.w, pk, acc);
        }
        if (++chunk == 7) {   // 56 elems: 6-bit count fields <=63, f16 sums <=~320
            chunk = 0;
#pragma unroll
            for (int b = 0; b < BINS; ++b) c[b] += (int)((pk >> (6 * b)) & 63u);
            pk = 0;
#pragma unroll
            for (int p = 0; p < 5; ++p) {
                __half2 h = __builtin_bit_cast(__half2, acc[p]);
                s[2 * p]     += __half2float(__low2half(h));
                s[2 * p + 1] += __half2float(__high2half(h));
                acc[p] = 0u;
            }
        }
    }
    const long long tail0 = n4 << 2;     // n % 4 remainder: block 0
    if (blockIdx.x == 0 && (long long)tid < (n - tail0))
        ghm_elem(pred[tail0 + tid], tgt[tail0 + tid], pk, acc);
#pragma unroll
    for (int b = 0; b < BINS; ++b) c[b] += (int)((pk >> (6 * b)) & 63u);
#pragma unroll
    for (int p = 0; p < 5; ++p) {
        __half2 h = __builtin_bit_cast(__half2, acc[p]);
        s[2 * p]     += __half2float(__low2half(h));
        s[2 * p + 1] += __half2float(__high2half(h));
    }

    // block reduce: shuffle tree per bin, then cross-wave via LDS (validated)
#pragma unroll
    for (int b = 0; b < BINS; ++b) {
        float v = s[b];
        int   k = c[b];
        for (int off = 32; off; off >>= 1) {
            v += __shfl_down(v, off);
            k += __shfl_down(k, off);
        }
        if (lane == 0) { rsum[wave][b] = v; rcnt[wave][b] = k; }
    }
    __syncthreads();
    if (tid < BINS) {
        int b = tid;
        float v = rsum[0][b] + rsum[1][b] + rsum[2][b] + rsum[3][b];
        int   k = rcnt[0][b] + rcnt[1][b] + rcnt[2][b] + rcnt[3][b];
        // fixed-point u64 accumulate: exact, order-independent, device-scope
        unsigned long long fv =
            (unsigned long long)((double)v * 67108864.0 + 0.5);  // 2^26
        atomicAdd(&gsum[b], fv);
        atomicAdd(&gcnt[b], (unsigned long long)(unsigned)k);
    }
    asm volatile("s_waitcnt vmcnt(0)" ::: "memory");  // adds at coherent point
    __syncthreads();

    __shared__ unsigned int is_last;
    if (tid == 0)
        is_last = (atomicAdd(done, 1u) == (unsigned)(nb - 1)) ? 1u : 0u;
    __syncthreads();
    if (!is_last) return;

    // winner: read 20 accumulators (one latency, lanes parallel), final math
    __shared__ double    ssum[BINS];
    __shared__ long long scnt[BINS];
    if (tid < BINS) {
        unsigned long long sv = __hip_atomic_load(&gsum[tid], __ATOMIC_RELAXED,
                                                  __HIP_MEMORY_SCOPE_AGENT);
        unsigned long long cv = __hip_atomic_load(&gcnt[tid], __ATOMIC_RELAXED,
                                                  __HIP_MEMORY_SCOPE_AGENT);
        ssum[tid] = (double)sv * (1.0 / 67108864.0);
        scnt[tid] = (long long)cv;
    }
    __syncthreads();
    if (tid == 0) {
        int nn = 0;
#pragma unroll
        for (int b = 0; b < BINS; ++b) nn += (scnt[b] > 0) ? 1 : 0;
        double loss = 0.0;
        if (nn > 0) {
#pragma unroll
            for (int b = 0; b < BINS; ++b)
                if (scnt[b] > 0)
                    loss += ssum[b] / ((double)scnt[b] * (double)nn);
        }
        out[0] = (float)loss;
    }
}

extern "C" void kernel_launch(void* const* d_in, const int* in_sizes, int n_in,
                              void* d_out, int out_size, void* d_ws, size_t ws_size,
                              hipStream_t stream) {
    const float* pred = (const float*)d_in[0];
    const float* tgt  = (const float*)d_in[1];
    float* out = (float*)d_out;
    const long long n = (long long)in_sizes[0];

    const int nb = 2048;
    unsigned long long* gsum = (unsigned long long*)d_ws;          // 80 B
    unsigned long long* gcnt = gsum + BINS;                        // 80 B
    unsigned int*       done = (unsigned int*)(gcnt + BINS);       // 4 B

    // zero accumulators + ticket every call (captured into the graph)
    hipMemsetAsync(d_ws, 0, 2 * BINS * sizeof(unsigned long long)
                             + sizeof(unsigned int), stream);
    ghm_fused<<<nb, 256, 0, stream>>>(pred, tgt, n, nb, gsum, gcnt, done, out);
}

// Round 19
// 45.540 us; speedup vs baseline: 1.8835x; 1.8835x over previous
//
#include <hip/hip_runtime.h>
#include <hip/hip_fp16.h>

#define BINS 10

typedef float f32x2 __attribute__((ext_vector_type(2)));

__device__ __forceinline__ unsigned pk_add_f16x2(unsigned a, unsigned b) {
    __half2 ha = __builtin_bit_cast(__half2, a);
    __half2 hb = __builtin_bit_cast(__half2, b);
    return __builtin_bit_cast(unsigned, __hadd2(ha, hb));   // v_pk_add_f16
}

// ===== ELEM MATH: byte-for-byte from R2/R8/R13/R15 (PASSED absmax 0.0). The
// z-form (R3-R7) fails on HW — banned. LDS atomics (R8/R14), volatile RMW
// chains (R9), fused epilogues (R16-R18) all banned/parked.
// Scatter: packed-f16 pair accumulators (R15, passed).
__device__ __forceinline__ void ghm_elem(float x, float tt,
                                         unsigned long long& pk,
                                         unsigned (&acc)[5]) {
    float t = __expf(-fabsf(x));                 // e^{-|x|}
    float u = 1.f + t;
    float r = __builtin_amdgcn_rcpf(u);          // ~1ulp approx, ample slack
    float sig = (x >= 0.f) ? r : t * r;          // sigmoid(x), all ranges
    float d = sig - tt;
    int idx = (int)(fabsf(d) * 10.f);            // trunc (validated R8/R10)
    idx = idx < 9 ? idx : 9;
    pk += 1ull << (6 * idx);                     // packed counts, 6b/bin
    float bce = fmaxf(x, 0.f) - x * tt + __logf(u);  // log1p(e^{-|x|}) = log(u)
    unsigned hv = (unsigned)__builtin_bit_cast(unsigned short, __float2half(bce));
    hv <<= ((idx & 1) << 4);                     // place in low/high half
    const int pair = idx >> 1;
#pragma unroll
    for (int p = 0; p < 5; ++p)                  // cmp + cndmask + pk_add
        acc[p] = pk_add_f16x2(acc[p], (pair == p) ? hv : 0u);
}

// L3-BYPASS PROBE: main-loop streams read via relaxed AGENT atomic b64 loads
// (sc0 sc1 device-coherent -> bypass per-XCD L2 and, per theory, the slow
// L3-hit serve path that pins delivery at ~3.4 TB/s / FETCH=64MB). These are
// ordinary vmcnt-tracked wave-wide loads; values bit-identical to plain loads.
__device__ __forceinline__ unsigned long long ld_agent_u64(
    const unsigned long long* p) {
    return __hip_atomic_load((unsigned long long*)p, __ATOMIC_RELAXED,
                             __HIP_MEMORY_SCOPE_AGENT);
}

__global__ __launch_bounds__(256) void ghm_pass1(
    const float* __restrict__ pred, const float* __restrict__ tgt,
    long long n, int nb,
    float* __restrict__ bsum, int* __restrict__ bcnt)
{
    __shared__ float rsum[4][BINS];
    __shared__ int   rcnt[4][BINS];

    const int tid  = threadIdx.x;
    const int lane = tid & 63;
    const int wave = tid >> 6;

    float s[BINS];
#pragma unroll
    for (int b = 0; b < BINS; ++b) s[b] = 0.f;
    unsigned acc[5];
#pragma unroll
    for (int p = 0; p < 5; ++p) acc[p] = 0u;
    unsigned long long pk = 0;
    int c[BINS];
#pragma unroll
    for (int b = 0; b < BINS; ++b) c[b] = 0;

    const long long n4 = n >> 2;                 // 16B quads
    const unsigned long long* pu = (const unsigned long long*)pred;
    const unsigned long long* tu = (const unsigned long long*)tgt;

    // Chunked contiguous partition (R11/R13). Per quad i: u64s {2i, 2i+1}.
    const long long qpb = (n4 + nb - 1) / nb;
    const long long q0  = (long long)blockIdx.x * qpb;
    const long long q1  = (q0 + qpb < n4) ? (q0 + qpb) : n4;

    int chunk = 0;
    for (long long i = q0 + tid; i < q1; i += 512) {   // unroll x2
        unsigned long long pa0 = ld_agent_u64(&pu[2 * i]);
        unsigned long long pa1 = ld_agent_u64(&pu[2 * i + 1]);
        unsigned long long ta0 = ld_agent_u64(&tu[2 * i]);
        unsigned long long ta1 = ld_agent_u64(&tu[2 * i + 1]);
        const long long j = i + 256;
        const bool has2 = (j < q1);
        unsigned long long pb0 = 0, pb1 = 0, tb0 = 0, tb1 = 0;
        if (has2) {
            pb0 = ld_agent_u64(&pu[2 * j]);
            pb1 = ld_agent_u64(&pu[2 * j + 1]);
            tb0 = ld_agent_u64(&tu[2 * j]);
            tb1 = ld_agent_u64(&tu[2 * j + 1]);
        }
        {
            f32x2 plo = __builtin_bit_cast(f32x2, pa0);
            f32x2 phi = __builtin_bit_cast(f32x2, pa1);
            f32x2 tlo = __builtin_bit_cast(f32x2, ta0);
            f32x2 thi = __builtin_bit_cast(f32x2, ta1);
            ghm_elem(plo.x, tlo.x, pk, acc);
            ghm_elem(plo.y, tlo.y, pk, acc);
            ghm_elem(phi.x, thi.x, pk, acc);
            ghm_elem(phi.y, thi.y, pk, acc);
        }
        if (has2) {
            f32x2 plo = __builtin_bit_cast(f32x2, pb0);
            f32x2 phi = __builtin_bit_cast(f32x2, pb1);
            f32x2 tlo = __builtin_bit_cast(f32x2, tb0);
            f32x2 thi = __builtin_bit_cast(f32x2, tb1);
            ghm_elem(plo.x, tlo.x, pk, acc);
            ghm_elem(plo.y, tlo.y, pk, acc);
            ghm_elem(phi.x, thi.x, pk, acc);
            ghm_elem(phi.y, thi.y, pk, acc);
        }
        if (++chunk == 7) {   // 56 elems: 6-bit count fields <=63, f16 sums <=~320
            chunk = 0;
#pragma unroll
            for (int b = 0; b < BINS; ++b) c[b] += (int)((pk >> (6 * b)) & 63u);
            pk = 0;
#pragma unroll
            for (int p = 0; p < 5; ++p) {
                __half2 h = __builtin_bit_cast(__half2, acc[p]);
                s[2 * p]     += __half2float(__low2half(h));
                s[2 * p + 1] += __half2float(__high2half(h));
                acc[p] = 0u;
            }
        }
    }
    const long long tail0 = n4 << 2;     // n % 4 remainder: block 0, plain loads
    if (blockIdx.x == 0 && (long long)tid < (n - tail0))
        ghm_elem(pred[tail0 + tid], tgt[tail0 + tid], pk, acc);
#pragma unroll
    for (int b = 0; b < BINS; ++b) c[b] += (int)((pk >> (6 * b)) & 63u);
#pragma unroll
    for (int p = 0; p < 5; ++p) {
        __half2 h = __builtin_bit_cast(__half2, acc[p]);
        s[2 * p]     += __half2float(__low2half(h));
        s[2 * p + 1] += __half2float(__high2half(h));
    }

    // block reduce: shuffle tree per bin, then cross-wave via LDS (validated)
#pragma unroll
    for (int b = 0; b < BINS; ++b) {
        float v = s[b];
        int   k = c[b];
        for (int off = 32; off; off >>= 1) {
            v += __shfl_down(v, off);
            k += __shfl_down(k, off);
        }
        if (lane == 0) { rsum[wave][b] = v; rcnt[wave][b] = k; }
    }
    __syncthreads();
    if (tid < BINS) {
        int b = tid;
        float v = rsum[0][b] + rsum[1][b] + rsum[2][b] + rsum[3][b];
        int   k = rcnt[0][b] + rcnt[1][b] + rcnt[2][b] + rcnt[3][b];
        bsum[(long long)b * nb + blockIdx.x] = v;   // bin-major partials
        bcnt[(long long)b * nb + blockIdx.x] = k;
    }
}

// 10 waves, one bin per wave: parallel strided loads, shuffle reduce.
// Byte-for-byte validated since R2.
__global__ __launch_bounds__(640) void ghm_pass2(
    const float* __restrict__ bsum, const int* __restrict__ bcnt,
    int nb, float* __restrict__ out)
{
    __shared__ double    ssum[BINS];
    __shared__ long long scnt[BINS];
    const int lane = threadIdx.x & 63;
    const int wave = threadIdx.x >> 6;   // 0..9 == bin

    double    acc = 0.0;
    long long cc  = 0;
    for (int i = lane; i < nb; i += 64) {
        acc += (double)bsum[(long long)wave * nb + i];
        cc  += (long long)bcnt[(long long)wave * nb + i];
    }
    for (int off = 32; off; off >>= 1) {
        acc += __shfl_down(acc, off);
        cc  += __shfl_down(cc, off);
    }
    if (lane == 0) { ssum[wave] = acc; scnt[wave] = cc; }
    __syncthreads();

    if (threadIdx.x == 0) {
        int n = 0;
#pragma unroll
        for (int b = 0; b < BINS; ++b) n += (scnt[b] > 0) ? 1 : 0;
        double loss = 0.0;
        if (n > 0) {
#pragma unroll
            for (int b = 0; b < BINS; ++b)
                if (scnt[b] > 0)
                    loss += ssum[b] / ((double)scnt[b] * (double)n);
        }
        out[0] = (float)loss;
    }
}

extern "C" void kernel_launch(void* const* d_in, const int* in_sizes, int n_in,
                              void* d_out, int out_size, void* d_ws, size_t ws_size,
                              hipStream_t stream) {
    const float* pred = (const float*)d_in[0];
    const float* tgt  = (const float*)d_in[1];
    float* out = (float*)d_out;
    const long long n = (long long)in_sizes[0];

    int nb = 2048;
    const size_t per_block = (size_t)BINS * (sizeof(float) + sizeof(int)); // 80 B
    while (nb > 1 && (size_t)nb * per_block > ws_size) nb >>= 1;

    float* bsum = (float*)d_ws;
    int*   bcnt = (int*)((char*)d_ws + (size_t)nb * BINS * sizeof(float));

    ghm_pass1<<<nb, 256, 0, stream>>>(pred, tgt, n, nb, bsum, bcnt);
    ghm_pass2<<<1, 640, 0, stream>>>(bsum, bcnt, nb, out);
}